// Round 22
// baseline (248.536 us; speedup 1.0000x reference)
//
#include <hip/hip_runtime.h>
#include <math.h>

#define TOKS 4096
#define HS   2048
#define QKV_N 3072
#define S_LEN 2048
#define NH   16
#define NKV  4
#define DH   128

typedef __attribute__((ext_vector_type(8))) short short8;
typedef __attribute__((ext_vector_type(4))) float f32x4;

static __device__ __forceinline__ unsigned short f2bf(float f) {
  unsigned u = __builtin_bit_cast(unsigned, f);
  u += 0x7fffu + ((u >> 16) & 1u);           // round-to-nearest-even
  return (unsigned short)(u >> 16);
}
static __device__ __forceinline__ float bf2f(unsigned short s) {
  unsigned u = (unsigned)s << 16;
  return __builtin_bit_cast(float, u);
}

// ---------------------------------------------------------------------------
// Fused input prep (1 launch), grid (64, 224):
//   y <  96 : w_qkv -> wqkvt (transpose+cvt)
//   y < 160 : w_o   -> wot   (transpose+cvt)   [wot DISJOINT from wqkvt]
//   y < 224 : hidden -> hb (cvt)
// ---------------------------------------------------------------------------
__global__ __launch_bounds__(256)
void prep_all(const float* __restrict__ hidden, const float* __restrict__ w_qkv,
              const float* __restrict__ w_o, unsigned short* __restrict__ hb,
              unsigned short* __restrict__ wqkvt, unsigned short* __restrict__ wot) {
  __shared__ float tile[32][33];
  const int x = blockIdx.x, y = blockIdx.y;

  if (y < 160) {                       // transpose sections
    const float* in; unsigned short* out; int ldin, c0;
    if (y < 96) { in = w_qkv; out = wqkvt; ldin = QKV_N; c0 = y * 32; }
    else        { in = w_o;   out = wot;   ldin = HS;    c0 = (y - 96) * 32; }
    const int r0 = x * 32;
    const int tx = threadIdx.x & 31, ty = threadIdx.x >> 5;  // 32 x 8
    #pragma unroll
    for (int i = 0; i < 4; ++i)
      tile[ty + i * 8][tx] = in[(size_t)(r0 + ty + i * 8) * ldin + c0 + tx];
    __syncthreads();
    #pragma unroll
    for (int i = 0; i < 4; ++i)
      out[(size_t)(c0 + ty + i * 8) * HS + r0 + tx] = f2bf(tile[tx][ty + i * 8]);
  } else {                             // cvt section
    const size_t bid = (size_t)(y - 160) * 64 + x;
    const size_t i = (bid * 256 + threadIdx.x) * 8;
    float4 a = *(const float4*)(hidden + i);
    float4 b = *(const float4*)(hidden + i + 4);
    short8 r;
    r[0] = f2bf(a.x); r[1] = f2bf(a.y); r[2] = f2bf(a.z); r[3] = f2bf(a.w);
    r[4] = f2bf(b.x); r[5] = f2bf(b.y); r[6] = f2bf(b.z); r[7] = f2bf(b.w);
    *(short8*)(hb + i) = r;
  }
}

// ---------------------------------------------------------------------------
// Fused RMSNorm+RoPE (+ V transpose), grid (TOKS, 6).
// Q pre-scaled by 1/sqrt(DH) * log2(e)  -> exp2-domain softmax in attn.
// ---------------------------------------------------------------------------
__global__ __launch_bounds__(256)
void norm_rope_v(const unsigned short* __restrict__ qkv, const int* __restrict__ positions,
                 const float* __restrict__ qw, const float* __restrict__ kw,
                 unsigned short* __restrict__ Qb, unsigned short* __restrict__ Kb,
                 unsigned short* __restrict__ Vt) {
  __shared__ unsigned short vtile[32][33];
  const int y = blockIdx.y;

  if (y == 5) {                        // V transpose section
    const int xid = blockIdx.x;
    if (xid >= 2048) return;
    const int bx = xid & 63, by = (xid >> 6) & 3, bz = xid >> 8;   // bz 0..7
    const unsigned short* in = qkv + (NH + NKV) * DH +
        (size_t)(bz >> 2) * S_LEN * QKV_N + (bz & 3) * DH;
    unsigned short* out = Vt + (size_t)bz * DH * S_LEN;
    const int r0 = bx * 32, c0 = by * 32;
    const int tx = threadIdx.x & 31, ty = threadIdx.x >> 5;
    #pragma unroll
    for (int i = 0; i < 4; ++i)
      vtile[ty + i * 8][tx] = in[(size_t)(r0 + ty + i * 8) * QKV_N + c0 + tx];
    __syncthreads();
    #pragma unroll
    for (int i = 0; i < 4; ++i)
      out[(size_t)(c0 + ty + i * 8) * S_LEN + r0 + tx] = vtile[tx][ty + i * 8];
    return;
  }

  const int tok  = blockIdx.x;
  const int slot = y * 4 + (threadIdx.x >> 6);   // 0..19
  const int lane = threadIdx.x & 63;
  const int b = tok >> 11, s = tok & 2047;

  const unsigned short* x; const float* wgt; unsigned short* outp; float scale;
  if (slot < NH) {
    x = qkv + (size_t)tok * QKV_N + slot * DH;  wgt = qw;
    outp = Qb + (((size_t)b * NH + slot) * S_LEN + s) * DH;
    scale = 0.08838834764831845f * 1.4426950408889634f;  // 1/sqrt(DH) * log2(e)
  } else {
    const int kh = slot - NH;
    x = qkv + (size_t)tok * QKV_N + NH * DH + kh * DH;  wgt = kw;
    outp = Kb + (((size_t)b * NKV + kh) * S_LEN + s) * DH;
    scale = 1.0f;
  }

  float x1 = bf2f(x[lane]), x2 = bf2f(x[lane + 64]);
  float ss = x1 * x1 + x2 * x2;
  #pragma unroll
  for (int o = 32; o > 0; o >>= 1) ss += __shfl_xor(ss, o, 64);
  const float rs = 1.0f / sqrtf(ss * (1.0f / 128.0f) + 1e-6f);
  const float n1 = x1 * rs * wgt[lane];
  const float n2 = x2 * rs * wgt[lane + 64];

  const float pos = (float)positions[tok];
  const float inv_freq = exp2f(-(float)lane * (13.287712379549449f / 64.0f));
  float sn, cs;
  sincosf(pos * inv_freq, &sn, &cs);

  outp[lane]      = f2bf((n1 * cs - n2 * sn) * scale);
  outp[lane + 64] = f2bf((n2 * cs + n1 * sn) * scale);
}

// ---------------------------------------------------------------------------
// 8-phase 256xNB bf16 MFMA GEMM + T1 XCD-aware block swizzle (nwg%8==0:
// 192 and 256 both qualify -> bijective). Same-XCD-consecutive blocks share
// the A row panel -> A L2-resident.
// ---------------------------------------------------------------------------
template <int OUT_BF16, int NB>
__global__ __launch_bounds__(512, 2)
void gemm256(const unsigned short* __restrict__ A, const unsigned short* __restrict__ Bt,
             void* __restrict__ Cv, int M, int N, int K) {
  constexpr int NW   = NB / 4;
  constexpr int NACC = NB / 64;
  constexpr int BL   = NB / 128;

  __shared__ __align__(16) unsigned short LA[2][256 * 64];
  __shared__ __align__(16) unsigned short LB[2][NB * 64];

  const int t = threadIdx.x, w = t >> 6, l = t & 63;
  const int lm = l & 15, lr = l >> 4;
  const int wr = w >> 2, wc = w & 3;
  const int nxt = gridDim.x, nwg = gridDim.x * gridDim.y;
  const int wid = blockIdx.x + gridDim.x * blockIdx.y;
  const int swz = (wid & 7) * (nwg >> 3) + (wid >> 3);   // T1, bijective (nwg%8==0)
  const int bn = (swz % nxt) * NB, bm = (swz / nxt) * 256;
  const int nkt = K >> 6;

  f32x4 acc[8][NACC];
  #pragma unroll
  for (int mi = 0; mi < 8; ++mi)
    #pragma unroll
    for (int ni = 0; ni < NACC; ++ni) acc[mi][ni] = {0.f, 0.f, 0.f, 0.f};

  auto stageA = [&](unsigned short* Lb, int half, int kt) {
    if (kt >= nkt) return;
    const int k0 = kt << 6;
    #pragma unroll
    for (int r = 0; r < 2; ++r) {
      const int row  = half * 128 + r * 64 + (t >> 3);
      const int slot = (t & 7) ^ (row & 7);
      const unsigned short* src = A + (size_t)(bm + row) * K + k0 + slot * 8;
      __builtin_amdgcn_global_load_lds(
          (const __attribute__((address_space(1))) void*)src,
          (__attribute__((address_space(3))) void*)(Lb + (half * 128 + r * 64 + w * 8) * 64),
          16, 0, 0);
    }
  };
  auto stageB = [&](unsigned short* Lb, int half, int kt) {
    if (kt >= nkt) return;
    const int k0 = kt << 6;
    #pragma unroll
    for (int r = 0; r < BL; ++r) {
      const int row  = half * (NB / 2) + r * 64 + (t >> 3);
      const int slot = (t & 7) ^ (row & 7);
      const unsigned short* src = Bt + (size_t)(bn + row) * K + k0 + slot * 8;
      __builtin_amdgcn_global_load_lds(
          (const __attribute__((address_space(1))) void*)src,
          (__attribute__((address_space(3))) void*)(Lb + (half * (NB / 2) + r * 64 + w * 8) * 64),
          16, 0, 0);
    }
  };

  stageB(&LB[0][0], 0, 0); stageB(&LB[0][0], 1, 0);
  stageA(&LA[0][0], 0, 0); stageA(&LA[0][0], 1, 0);
  stageB(&LB[1][0], 0, 1); stageB(&LB[1][0], 1, 1);
  if constexpr (NB == 256) asm volatile("s_waitcnt vmcnt(4)" ::: "memory");
  else                     asm volatile("s_waitcnt vmcnt(2)" ::: "memory");
  __builtin_amdgcn_s_barrier();

  const int niter = nkt >> 1;
  for (int i = 0; i < niter; ++i) {
    const int t0 = i * 2;
    short8 bfr[NACC][2];
    #pragma unroll
    for (int p = 0; p < 8; ++p) {
      const int buf = p >> 2, q = p & 3;
      const unsigned short* La = &LA[buf][0];
      const unsigned short* Lb = &LB[buf][0];

      if (q == 0) {
        #pragma unroll
        for (int ni = 0; ni < NACC; ++ni)
          #pragma unroll
          for (int ks = 0; ks < 2; ++ks) {
            const int row = wc * NW + ni * 16 + lm;
            bfr[ni][ks] = *(const short8*)(Lb + row * 64 +
                                           ((ks * 32 + lr * 8) ^ ((row & 7) << 3)));
          }
      }
      short8 af[2][2];
      #pragma unroll
      for (int mi2 = 0; mi2 < 2; ++mi2)
        #pragma unroll
        for (int ks = 0; ks < 2; ++ks) {
          const int row = wr * 128 + (q * 2 + mi2) * 16 + lm;
          af[mi2][ks] = *(const short8*)(La + row * 64 +
                                         ((ks * 32 + lr * 8) ^ ((row & 7) << 3)));
        }

      switch (p) {
        case 0: stageA(&LA[1][0], 0, t0 + 1); break;
        case 1: stageA(&LA[1][0], 1, t0 + 1); break;
        case 2: stageB(&LB[0][0], 0, t0 + 2); break;
        case 3: stageB(&LB[0][0], 1, t0 + 2); break;
        case 4: stageA(&LA[0][0], 0, t0 + 2); break;
        case 5: stageA(&LA[0][0], 1, t0 + 2); break;
        case 6: stageB(&LB[1][0], 0, t0 + 3); break;
        case 7: stageB(&LB[1][0], 1, t0 + 3); break;
      }

      __builtin_amdgcn_s_barrier();
      asm volatile("s_waitcnt lgkmcnt(0)" ::: "memory");
      __builtin_amdgcn_sched_barrier(0);

      __builtin_amdgcn_s_setprio(1);
      #pragma unroll
      for (int mi2 = 0; mi2 < 2; ++mi2)
        #pragma unroll
        for (int ni = 0; ni < NACC; ++ni)
          #pragma unroll
          for (int ks = 0; ks < 2; ++ks)
            acc[q * 2 + mi2][ni] = __builtin_amdgcn_mfma_f32_16x16x32_bf16(
                af[mi2][ks], bfr[ni][ks], acc[q * 2 + mi2][ni], 0, 0, 0);
      __builtin_amdgcn_s_setprio(0);

      if (q == 3) {
        if (i == niter - 1) asm volatile("s_waitcnt vmcnt(0)" ::: "memory");
        else if constexpr (NB == 256) asm volatile("s_waitcnt vmcnt(4)" ::: "memory");
        else                          asm volatile("s_waitcnt vmcnt(2)" ::: "memory");
      }
      __builtin_amdgcn_s_barrier();
    }
  }

  #pragma unroll
  for (int mi = 0; mi < 8; ++mi)
    #pragma unroll
    for (int ni = 0; ni < NACC; ++ni)
      #pragma unroll
      for (int j = 0; j < 4; ++j) {
        const size_t idx =
            (size_t)(bm + wr * 128 + mi * 16 + lr * 4 + j) * N + bn + wc * NW + ni * 16 + lm;
        if constexpr (OUT_BF16) ((unsigned short*)Cv)[idx] = f2bf(acc[mi][ni][j]);
        else                    ((float*)Cv)[idx] = acc[mi][ni][j];
      }
}

// ---------------------------------------------------------------------------
// MFMA causal GQA flash attention — R18 structure, exp2-domain softmax
// (Q pre-scaled by log2e at prep; v_exp_f32 is natively 2^x -> saves the
// per-exp multiply). m_run in log2 units.
// ---------------------------------------------------------------------------
#define M_INIT2 17.312340490667560f   // 12.0 * log2(e)
#define P_CAP   2981.0f               // e^8 (P domain unchanged)

__global__ __launch_bounds__(512)
void attn_mfma(const unsigned short* __restrict__ Qb, const unsigned short* __restrict__ Kb,
               const unsigned short* __restrict__ Vt, unsigned short* __restrict__ att) {
  __shared__ unsigned short Ks_[2][64 * 128];   // 32 KB
  __shared__ unsigned short Vs_[2][128 * 64];   // 32 KB
  __shared__ unsigned short Pl[8][16 * 64];     // 16 KB

  const int x  = blockIdx.x;
  const int b  = blockIdx.z;
  const int qb = b ? x : 15 - x;                 // complementary pairing
  const int h  = blockIdx.y;
  const int kvh = h >> 2;
  const int t = threadIdx.x, w = t >> 6, l = t & 63;
  const int lm = l & 15, lr = l >> 4;
  const int row0 = qb * 128 + w * 16;            // wave's first q row

  const unsigned short* qbase = Qb + ((size_t)(b * NH + h)) * S_LEN * DH;
  const unsigned short* kbase = Kb + ((size_t)(b * NKV + kvh)) * S_LEN * DH;
  const unsigned short* vtbase = Vt + ((size_t)(b * NKV + kvh)) * DH * S_LEN;

  short8 qf[4];
  #pragma unroll
  for (int kc = 0; kc < 4; ++kc)
    qf[kc] = *(const short8*)(qbase + (size_t)(row0 + lm) * DH + kc * 32 + lr * 8);

  short8 ones;
  #pragma unroll
  for (int i = 0; i < 8; ++i) ones[i] = (short)0x3F80;   // bf16 1.0

  f32x4 o[8];
  #pragma unroll
  for (int ng = 0; ng < 8; ++ng) o[ng] = {0.f, 0.f, 0.f, 0.f};
  f32x4 lacc = {0.f, 0.f, 0.f, 0.f};
  float m_run[4];
  #pragma unroll
  for (int j = 0; j < 4; ++j) m_run[j] = M_INIT2;

  auto stage = [&](int bufi, int kb0) {
    #pragma unroll
    for (int i = 0; i < 2; ++i) {
      const int rk = i * 32 + w * 4 + (l >> 4);          // K row 0..63
      const unsigned short* gk =
          kbase + (size_t)(kb0 + rk) * DH + (((l & 15) ^ (rk & 7)) * 8);
      __builtin_amdgcn_global_load_lds(
          (const __attribute__((address_space(1))) void*)gk,
          (__attribute__((address_space(3))) void*)(&Ks_[bufi][(i * 512 + w * 64) * 8]),
          16, 0, 0);
      const int rv = i * 64 + w * 8 + (l >> 3);          // V row (d) 0..127
      const unsigned short* gv =
          vtbase + (size_t)rv * S_LEN + kb0 + (((l & 7) ^ (rv & 7)) * 8);
      __builtin_amdgcn_global_load_lds(
          (const __attribute__((address_space(1))) void*)gv,
          (__attribute__((address_space(3))) void*)(&Vs_[bufi][(i * 512 + w * 64) * 8]),
          16, 0, 0);
    }
  };

  const int nkt = qb * 2 + 2;
  stage(0, 0);
  __syncthreads();

  for (int kt = 0; kt < nkt; ++kt) {
    const int kb0 = kt * 64;
    if (kt + 1 < nkt) stage((kt + 1) & 1, kb0 + 64);

    if (kb0 <= row0 + 15) {
      const unsigned short* Kc = Ks_[kt & 1];
      const unsigned short* Vc = Vs_[kt & 1];
      const int rsw = (lm & 7) << 3;
      const int ng2 = min(4, ((row0 + 15 - kb0) >> 4) + 1);   // live n2 groups

      // ---- S = Q K^T (skip fully-masked groups) ----
      f32x4 s[4];
      #pragma unroll
      for (int n2 = 0; n2 < 4; ++n2) s[n2] = {0.f, 0.f, 0.f, 0.f};
      __builtin_amdgcn_s_setprio(1);
      #pragma unroll
      for (int n2 = 0; n2 < 4; ++n2) {
        if (n2 < ng2) {
          #pragma unroll
          for (int kc = 0; kc < 4; ++kc) {
            const short8 kf = *(const short8*)(Kc + (n2 * 16 + lm) * 128 +
                                               ((kc * 32 + lr * 8) ^ rsw));
            s[n2] = __builtin_amdgcn_mfma_f32_16x16x32_bf16(qf[kc], kf, s[n2], 0, 0, 0);
          }
        }
      }
      __builtin_amdgcn_s_setprio(0);

      // ---- causal mask (boundary tiles only; live groups) ----
      if (kb0 + 63 > row0) {
        const int qi = row0 + lr * 4;
        #pragma unroll
        for (int n2 = 0; n2 < 4; ++n2) {
          if (n2 < ng2) {
            const int kvi = kb0 + n2 * 16 + lm;
            #pragma unroll
            for (int j = 0; j < 4; ++j)
              if (kvi > qi + j) s[n2][j] = -1e30f;
          }
        }
      }

      // ---- fast softmax: P = exp2(S2 - m2), live groups only ----
      float pm = 0.f;
      #pragma unroll
      for (int n2 = 0; n2 < 4; ++n2) {
        if (n2 < ng2) {
          #pragma unroll
          for (int j = 0; j < 4; ++j) {
            const float p = exp2f(s[n2][j] - m_run[j]);
            s[n2][j] = p;
            pm = fmaxf(pm, p);
          }
        }
      }

      if (!__all(pm <= P_CAP)) {
        // slow path (rare): per-row P-max via shfl chains; rescale rows > e^8
        #pragma unroll
        for (int j = 0; j < 4; ++j) {
          float v = fmaxf(fmaxf(s[0][j], s[1][j]), fmaxf(s[2][j], s[3][j]));
          v = fmaxf(v, __shfl_xor(v, 1, 64));
          v = fmaxf(v, __shfl_xor(v, 2, 64));
          v = fmaxf(v, __shfl_xor(v, 4, 64));
          v = fmaxf(v, __shfl_xor(v, 8, 64));
          if (v > P_CAP) {
            const float al = 1.0f / v;            // = exp2(m2_old - m2_new)
            m_run[j] += __log2f(v);
            lacc[j] *= al;
            #pragma unroll
            for (int n2 = 0; n2 < 4; ++n2) s[n2][j] *= al;
            #pragma unroll
            for (int ng = 0; ng < 8; ++ng) o[ng][j] *= al;
          }
        }
      }

      // ---- store P (swizzled; zeros for dead groups) ----
      #pragma unroll
      for (int j = 0; j < 4; ++j) {
        const int prow = lr * 4 + j;
        unsigned short* Pw = &Pl[w][prow * 64];
        const int sw = (prow & 7) << 3;
        Pw[lm ^ sw]        = f2bf(s[0][j]);
        Pw[(16 + lm) ^ sw] = f2bf(s[1][j]);
        Pw[(32 + lm) ^ sw] = f2bf(s[2][j]);
        Pw[(48 + lm) ^ sw] = f2bf(s[3][j]);
      }
      __asm__ volatile("s_waitcnt lgkmcnt(0)" ::: "memory");

      // ---- O += P V ;  l += P @ ones ----
      short8 pf[2];
      #pragma unroll
      for (int k2 = 0; k2 < 2; ++k2)
        pf[k2] = *(const short8*)(&Pl[w][lm * 64 + ((k2 * 32 + lr * 8) ^ rsw)]);
      __builtin_amdgcn_s_setprio(1);
      lacc = __builtin_amdgcn_mfma_f32_16x16x32_bf16(pf[0], ones, lacc, 0, 0, 0);
      lacc = __builtin_amdgcn_mfma_f32_16x16x32_bf16(pf[1], ones, lacc, 0, 0, 0);
      #pragma unroll
      for (int ng = 0; ng < 8; ++ng) {
        const short8 vf0 = *(const short8*)(Vc + (ng * 16 + lm) * 64 + ((lr * 8) ^ rsw));
        const short8 vf1 = *(const short8*)(Vc + (ng * 16 + lm) * 64 + ((32 + lr * 8) ^ rsw));
        o[ng] = __builtin_amdgcn_mfma_f32_16x16x32_bf16(pf[0], vf0, o[ng], 0, 0, 0);
        o[ng] = __builtin_amdgcn_mfma_f32_16x16x32_bf16(pf[1], vf1, o[ng], 0, 0, 0);
      }
      __builtin_amdgcn_s_setprio(0);
    }
    __syncthreads();
  }

  // ---- epilogue ----
  #pragma unroll
  for (int j = 0; j < 4; ++j) {
    const float linv = 1.0f / lacc[j];
    unsigned short* ar =
        att + ((size_t)(b * S_LEN) + row0 + lr * 4 + j) * (NH * DH) + h * DH + lm;
    #pragma unroll
    for (int ng = 0; ng < 8; ++ng) ar[ng * 16] = f2bf(o[ng][j] * linv);
  }
}

// ---------------------------------------------------------------------------
extern "C" void kernel_launch(void* const* d_in, const int* in_sizes, int n_in,
                              void* d_out, int out_size, void* d_ws, size_t ws_size,
                              hipStream_t stream) {
  const int*   positions = (const int*)  d_in[0];
  const float* hidden    = (const float*)d_in[1];
  const float* w_qkv     = (const float*)d_in[2];
  const float* w_o       = (const float*)d_in[3];
  const float* q_norm_w  = (const float*)d_in[4];
  const float* k_norm_w  = (const float*)d_in[5];
  float* out = (float*)d_out;

  // Workspace map (disjoint w.r.t. concurrent writers; see R21 fix):
  //   ws[ 0.0M, 25.2M)  qkvb / att(reuse)
  //   ws[25.2M, 33.6M)  wot
  //   ws[50.3M, 67.1M)  hb / Qb(reuse)
  //   ws[67.1M, 79.7M)  wqkvt (dies after qkv GEMM)
  //   ws[67.1M, 71.3M)  Kb ; ws[71.3M, 75.5M) Vt (written after wqkvt dead)
  char* ws = (char*)d_ws;
  unsigned short* qkvb  = (unsigned short*)ws;
  unsigned short* att   = (unsigned short*)ws;
  unsigned short* wot   = (unsigned short*)(ws + 25165824);
  char* region = ws + (size_t)TOKS * QKV_N * 4;                 // +50,331,648
  unsigned short* hb    = (unsigned short*)region;
  unsigned short* Qb    = (unsigned short*)region;
  unsigned short* wqkvt = (unsigned short*)(region + 16777216);
  unsigned short* Kb    = (unsigned short*)(region + 16777216);
  unsigned short* Vt    = (unsigned short*)(region + 20971520);

  prep_all<<<dim3(64, 224), 256, 0, stream>>>(hidden, w_qkv, w_o, hb, wqkvt, wot);
  gemm256<1, 256><<<dim3(QKV_N / 256, TOKS / 256), 512, 0, stream>>>(
      hb, wqkvt, qkvb, TOKS, QKV_N, HS);
  norm_rope_v<<<dim3(TOKS, 6), 256, 0, stream>>>(
      qkvb, positions, q_norm_w, k_norm_w, Qb, Kb, Vt);
  attn_mfma<<<dim3(16, NH, 2), 512, 0, stream>>>(Qb, Kb, Vt, att);
  gemm256<0, 128><<<dim3(HS / 128, TOKS / 256), 512, 0, stream>>>(
      att, wot, out, TOKS, HS, HS);
}

// Round 23
// 240.801 us; speedup vs baseline: 1.0321x; 1.0321x over previous
//
#include <hip/hip_runtime.h>
#include <math.h>

#define TOKS 4096
#define HS   2048
#define QKV_N 3072
#define S_LEN 2048
#define NH   16
#define NKV  4
#define DH   128

typedef __attribute__((ext_vector_type(8))) short short8;
typedef __attribute__((ext_vector_type(4))) float f32x4;

static __device__ __forceinline__ unsigned short f2bf(float f) {
  unsigned u = __builtin_bit_cast(unsigned, f);
  u += 0x7fffu + ((u >> 16) & 1u);           // round-to-nearest-even
  return (unsigned short)(u >> 16);
}
static __device__ __forceinline__ float bf2f(unsigned short s) {
  unsigned u = (unsigned)s << 16;
  return __builtin_bit_cast(float, u);
}

// ---------------------------------------------------------------------------
// Fused input prep (1 launch), grid (64, 224):
//   y <  96 : w_qkv -> wqkvt (transpose+cvt)
//   y < 160 : w_o   -> wot   (transpose+cvt)   [wot DISJOINT from wqkvt]
//   y < 224 : hidden -> hb (cvt)
// ---------------------------------------------------------------------------
__global__ __launch_bounds__(256)
void prep_all(const float* __restrict__ hidden, const float* __restrict__ w_qkv,
              const float* __restrict__ w_o, unsigned short* __restrict__ hb,
              unsigned short* __restrict__ wqkvt, unsigned short* __restrict__ wot) {
  __shared__ float tile[32][33];
  const int x = blockIdx.x, y = blockIdx.y;

  if (y < 160) {                       // transpose sections
    const float* in; unsigned short* out; int ldin, c0;
    if (y < 96) { in = w_qkv; out = wqkvt; ldin = QKV_N; c0 = y * 32; }
    else        { in = w_o;   out = wot;   ldin = HS;    c0 = (y - 96) * 32; }
    const int r0 = x * 32;
    const int tx = threadIdx.x & 31, ty = threadIdx.x >> 5;  // 32 x 8
    #pragma unroll
    for (int i = 0; i < 4; ++i)
      tile[ty + i * 8][tx] = in[(size_t)(r0 + ty + i * 8) * ldin + c0 + tx];
    __syncthreads();
    #pragma unroll
    for (int i = 0; i < 4; ++i)
      out[(size_t)(c0 + ty + i * 8) * HS + r0 + tx] = f2bf(tile[tx][ty + i * 8]);
  } else {                             // cvt section
    const size_t bid = (size_t)(y - 160) * 64 + x;
    const size_t i = (bid * 256 + threadIdx.x) * 8;
    float4 a = *(const float4*)(hidden + i);
    float4 b = *(const float4*)(hidden + i + 4);
    short8 r;
    r[0] = f2bf(a.x); r[1] = f2bf(a.y); r[2] = f2bf(a.z); r[3] = f2bf(a.w);
    r[4] = f2bf(b.x); r[5] = f2bf(b.y); r[6] = f2bf(b.z); r[7] = f2bf(b.w);
    *(short8*)(hb + i) = r;
  }
}

// ---------------------------------------------------------------------------
// Fused RMSNorm+RoPE (+ V transpose), grid (TOKS, 6).
// Q pre-scaled by 1/sqrt(DH).  (R21 numerics — exp2 reverted: plain exp2f is
// the slow libm path, measured +9us on attn in R22.)
// ---------------------------------------------------------------------------
__global__ __launch_bounds__(256)
void norm_rope_v(const unsigned short* __restrict__ qkv, const int* __restrict__ positions,
                 const float* __restrict__ qw, const float* __restrict__ kw,
                 unsigned short* __restrict__ Qb, unsigned short* __restrict__ Kb,
                 unsigned short* __restrict__ Vt) {
  __shared__ unsigned short vtile[32][33];
  const int y = blockIdx.y;

  if (y == 5) {                        // V transpose section
    const int xid = blockIdx.x;
    if (xid >= 2048) return;
    const int bx = xid & 63, by = (xid >> 6) & 3, bz = xid >> 8;   // bz 0..7
    const unsigned short* in = qkv + (NH + NKV) * DH +
        (size_t)(bz >> 2) * S_LEN * QKV_N + (bz & 3) * DH;
    unsigned short* out = Vt + (size_t)bz * DH * S_LEN;
    const int r0 = bx * 32, c0 = by * 32;
    const int tx = threadIdx.x & 31, ty = threadIdx.x >> 5;
    #pragma unroll
    for (int i = 0; i < 4; ++i)
      vtile[ty + i * 8][tx] = in[(size_t)(r0 + ty + i * 8) * QKV_N + c0 + tx];
    __syncthreads();
    #pragma unroll
    for (int i = 0; i < 4; ++i)
      out[(size_t)(c0 + ty + i * 8) * S_LEN + r0 + tx] = vtile[tx][ty + i * 8];
    return;
  }

  const int tok  = blockIdx.x;
  const int slot = y * 4 + (threadIdx.x >> 6);   // 0..19
  const int lane = threadIdx.x & 63;
  const int b = tok >> 11, s = tok & 2047;

  const unsigned short* x; const float* wgt; unsigned short* outp; float scale;
  if (slot < NH) {
    x = qkv + (size_t)tok * QKV_N + slot * DH;  wgt = qw;
    outp = Qb + (((size_t)b * NH + slot) * S_LEN + s) * DH;
    scale = 0.08838834764831845f;               // 1/sqrt(DH)
  } else {
    const int kh = slot - NH;
    x = qkv + (size_t)tok * QKV_N + NH * DH + kh * DH;  wgt = kw;
    outp = Kb + (((size_t)b * NKV + kh) * S_LEN + s) * DH;
    scale = 1.0f;
  }

  float x1 = bf2f(x[lane]), x2 = bf2f(x[lane + 64]);
  float ss = x1 * x1 + x2 * x2;
  #pragma unroll
  for (int o = 32; o > 0; o >>= 1) ss += __shfl_xor(ss, o, 64);
  const float rs = 1.0f / sqrtf(ss * (1.0f / 128.0f) + 1e-6f);
  const float n1 = x1 * rs * wgt[lane];
  const float n2 = x2 * rs * wgt[lane + 64];

  const float pos = (float)positions[tok];
  const float inv_freq = exp2f(-(float)lane * (13.287712379549449f / 64.0f));
  float sn, cs;
  sincosf(pos * inv_freq, &sn, &cs);

  outp[lane]      = f2bf((n1 * cs - n2 * sn) * scale);
  outp[lane + 64] = f2bf((n2 * cs + n1 * sn) * scale);
}

// ---------------------------------------------------------------------------
// 8-phase 256xNB bf16 MFMA GEMM + T1 XCD-aware block swizzle (kept: measured
// ~+3us on the GEMM pair in R22). nwg%8==0 for both grids -> bijective.
// ---------------------------------------------------------------------------
template <int OUT_BF16, int NB>
__global__ __launch_bounds__(512, 2)
void gemm256(const unsigned short* __restrict__ A, const unsigned short* __restrict__ Bt,
             void* __restrict__ Cv, int M, int N, int K) {
  constexpr int NW   = NB / 4;
  constexpr int NACC = NB / 64;
  constexpr int BL   = NB / 128;

  __shared__ __align__(16) unsigned short LA[2][256 * 64];
  __shared__ __align__(16) unsigned short LB[2][NB * 64];

  const int t = threadIdx.x, w = t >> 6, l = t & 63;
  const int lm = l & 15, lr = l >> 4;
  const int wr = w >> 2, wc = w & 3;
  const int nxt = gridDim.x, nwg = gridDim.x * gridDim.y;
  const int wid = blockIdx.x + gridDim.x * blockIdx.y;
  const int swz = (wid & 7) * (nwg >> 3) + (wid >> 3);   // T1, bijective (nwg%8==0)
  const int bn = (swz % nxt) * NB, bm = (swz / nxt) * 256;
  const int nkt = K >> 6;

  f32x4 acc[8][NACC];
  #pragma unroll
  for (int mi = 0; mi < 8; ++mi)
    #pragma unroll
    for (int ni = 0; ni < NACC; ++ni) acc[mi][ni] = {0.f, 0.f, 0.f, 0.f};

  auto stageA = [&](unsigned short* Lb, int half, int kt) {
    if (kt >= nkt) return;
    const int k0 = kt << 6;
    #pragma unroll
    for (int r = 0; r < 2; ++r) {
      const int row  = half * 128 + r * 64 + (t >> 3);
      const int slot = (t & 7) ^ (row & 7);
      const unsigned short* src = A + (size_t)(bm + row) * K + k0 + slot * 8;
      __builtin_amdgcn_global_load_lds(
          (const __attribute__((address_space(1))) void*)src,
          (__attribute__((address_space(3))) void*)(Lb + (half * 128 + r * 64 + w * 8) * 64),
          16, 0, 0);
    }
  };
  auto stageB = [&](unsigned short* Lb, int half, int kt) {
    if (kt >= nkt) return;
    const int k0 = kt << 6;
    #pragma unroll
    for (int r = 0; r < BL; ++r) {
      const int row  = half * (NB / 2) + r * 64 + (t >> 3);
      const int slot = (t & 7) ^ (row & 7);
      const unsigned short* src = Bt + (size_t)(bn + row) * K + k0 + slot * 8;
      __builtin_amdgcn_global_load_lds(
          (const __attribute__((address_space(1))) void*)src,
          (__attribute__((address_space(3))) void*)(Lb + (half * (NB / 2) + r * 64 + w * 8) * 64),
          16, 0, 0);
    }
  };

  stageB(&LB[0][0], 0, 0); stageB(&LB[0][0], 1, 0);
  stageA(&LA[0][0], 0, 0); stageA(&LA[0][0], 1, 0);
  stageB(&LB[1][0], 0, 1); stageB(&LB[1][0], 1, 1);
  if constexpr (NB == 256) asm volatile("s_waitcnt vmcnt(4)" ::: "memory");
  else                     asm volatile("s_waitcnt vmcnt(2)" ::: "memory");
  __builtin_amdgcn_s_barrier();

  const int niter = nkt >> 1;
  for (int i = 0; i < niter; ++i) {
    const int t0 = i * 2;
    short8 bfr[NACC][2];
    #pragma unroll
    for (int p = 0; p < 8; ++p) {
      const int buf = p >> 2, q = p & 3;
      const unsigned short* La = &LA[buf][0];
      const unsigned short* Lb = &LB[buf][0];

      if (q == 0) {
        #pragma unroll
        for (int ni = 0; ni < NACC; ++ni)
          #pragma unroll
          for (int ks = 0; ks < 2; ++ks) {
            const int row = wc * NW + ni * 16 + lm;
            bfr[ni][ks] = *(const short8*)(Lb + row * 64 +
                                           ((ks * 32 + lr * 8) ^ ((row & 7) << 3)));
          }
      }
      short8 af[2][2];
      #pragma unroll
      for (int mi2 = 0; mi2 < 2; ++mi2)
        #pragma unroll
        for (int ks = 0; ks < 2; ++ks) {
          const int row = wr * 128 + (q * 2 + mi2) * 16 + lm;
          af[mi2][ks] = *(const short8*)(La + row * 64 +
                                         ((ks * 32 + lr * 8) ^ ((row & 7) << 3)));
        }

      switch (p) {
        case 0: stageA(&LA[1][0], 0, t0 + 1); break;
        case 1: stageA(&LA[1][0], 1, t0 + 1); break;
        case 2: stageB(&LB[0][0], 0, t0 + 2); break;
        case 3: stageB(&LB[0][0], 1, t0 + 2); break;
        case 4: stageA(&LA[0][0], 0, t0 + 2); break;
        case 5: stageA(&LA[0][0], 1, t0 + 2); break;
        case 6: stageB(&LB[1][0], 0, t0 + 3); break;
        case 7: stageB(&LB[1][0], 1, t0 + 3); break;
      }

      __builtin_amdgcn_s_barrier();
      asm volatile("s_waitcnt lgkmcnt(0)" ::: "memory");
      __builtin_amdgcn_sched_barrier(0);

      __builtin_amdgcn_s_setprio(1);
      #pragma unroll
      for (int mi2 = 0; mi2 < 2; ++mi2)
        #pragma unroll
        for (int ni = 0; ni < NACC; ++ni)
          #pragma unroll
          for (int ks = 0; ks < 2; ++ks)
            acc[q * 2 + mi2][ni] = __builtin_amdgcn_mfma_f32_16x16x32_bf16(
                af[mi2][ks], bfr[ni][ks], acc[q * 2 + mi2][ni], 0, 0, 0);
      __builtin_amdgcn_s_setprio(0);

      if (q == 3) {
        if (i == niter - 1) asm volatile("s_waitcnt vmcnt(0)" ::: "memory");
        else if constexpr (NB == 256) asm volatile("s_waitcnt vmcnt(4)" ::: "memory");
        else                          asm volatile("s_waitcnt vmcnt(2)" ::: "memory");
      }
      __builtin_amdgcn_s_barrier();
    }
  }

  #pragma unroll
  for (int mi = 0; mi < 8; ++mi)
    #pragma unroll
    for (int ni = 0; ni < NACC; ++ni)
      #pragma unroll
      for (int j = 0; j < 4; ++j) {
        const size_t idx =
            (size_t)(bm + wr * 128 + mi * 16 + lr * 4 + j) * N + bn + wc * NW + ni * 16 + lm;
        if constexpr (OUT_BF16) ((unsigned short*)Cv)[idx] = f2bf(acc[mi][ni][j]);
        else                    ((float*)Cv)[idx] = acc[mi][ni][j];
      }
}

// ---------------------------------------------------------------------------
// MFMA causal GQA flash attention — R21 numerics restored (__expf fast-path
// softmax; exp2f reverted: libm exp2f costs +4 VALUBusy pts, +9us).
// ---------------------------------------------------------------------------
#define M_INIT 12.0f
#define P_CAP  2981.0f     // e^8

__global__ __launch_bounds__(512)
void attn_mfma(const unsigned short* __restrict__ Qb, const unsigned short* __restrict__ Kb,
               const unsigned short* __restrict__ Vt, unsigned short* __restrict__ att) {
  __shared__ unsigned short Ks_[2][64 * 128];   // 32 KB
  __shared__ unsigned short Vs_[2][128 * 64];   // 32 KB
  __shared__ unsigned short Pl[8][16 * 64];     // 16 KB

  const int x  = blockIdx.x;
  const int b  = blockIdx.z;
  const int qb = b ? x : 15 - x;                 // complementary pairing
  const int h  = blockIdx.y;
  const int kvh = h >> 2;
  const int t = threadIdx.x, w = t >> 6, l = t & 63;
  const int lm = l & 15, lr = l >> 4;
  const int row0 = qb * 128 + w * 16;            // wave's first q row

  const unsigned short* qbase = Qb + ((size_t)(b * NH + h)) * S_LEN * DH;
  const unsigned short* kbase = Kb + ((size_t)(b * NKV + kvh)) * S_LEN * DH;
  const unsigned short* vtbase = Vt + ((size_t)(b * NKV + kvh)) * DH * S_LEN;

  short8 qf[4];
  #pragma unroll
  for (int kc = 0; kc < 4; ++kc)
    qf[kc] = *(const short8*)(qbase + (size_t)(row0 + lm) * DH + kc * 32 + lr * 8);

  short8 ones;
  #pragma unroll
  for (int i = 0; i < 8; ++i) ones[i] = (short)0x3F80;   // bf16 1.0

  f32x4 o[8];
  #pragma unroll
  for (int ng = 0; ng < 8; ++ng) o[ng] = {0.f, 0.f, 0.f, 0.f};
  f32x4 lacc = {0.f, 0.f, 0.f, 0.f};
  float m_run[4];
  #pragma unroll
  for (int j = 0; j < 4; ++j) m_run[j] = M_INIT;

  auto stage = [&](int bufi, int kb0) {
    #pragma unroll
    for (int i = 0; i < 2; ++i) {
      const int rk = i * 32 + w * 4 + (l >> 4);          // K row 0..63
      const unsigned short* gk =
          kbase + (size_t)(kb0 + rk) * DH + (((l & 15) ^ (rk & 7)) * 8);
      __builtin_amdgcn_global_load_lds(
          (const __attribute__((address_space(1))) void*)gk,
          (__attribute__((address_space(3))) void*)(&Ks_[bufi][(i * 512 + w * 64) * 8]),
          16, 0, 0);
      const int rv = i * 64 + w * 8 + (l >> 3);          // V row (d) 0..127
      const unsigned short* gv =
          vtbase + (size_t)rv * S_LEN + kb0 + (((l & 7) ^ (rv & 7)) * 8);
      __builtin_amdgcn_global_load_lds(
          (const __attribute__((address_space(1))) void*)gv,
          (__attribute__((address_space(3))) void*)(&Vs_[bufi][(i * 512 + w * 64) * 8]),
          16, 0, 0);
    }
  };

  const int nkt = qb * 2 + 2;
  stage(0, 0);
  __syncthreads();

  for (int kt = 0; kt < nkt; ++kt) {
    const int kb0 = kt * 64;
    if (kt + 1 < nkt) stage((kt + 1) & 1, kb0 + 64);

    if (kb0 <= row0 + 15) {
      const unsigned short* Kc = Ks_[kt & 1];
      const unsigned short* Vc = Vs_[kt & 1];
      const int rsw = (lm & 7) << 3;
      const int ng2 = min(4, ((row0 + 15 - kb0) >> 4) + 1);   // live n2 groups

      // ---- S = Q K^T (skip fully-masked groups) ----
      f32x4 s[4];
      #pragma unroll
      for (int n2 = 0; n2 < 4; ++n2) s[n2] = {0.f, 0.f, 0.f, 0.f};
      __builtin_amdgcn_s_setprio(1);
      #pragma unroll
      for (int n2 = 0; n2 < 4; ++n2) {
        if (n2 < ng2) {
          #pragma unroll
          for (int kc = 0; kc < 4; ++kc) {
            const short8 kf = *(const short8*)(Kc + (n2 * 16 + lm) * 128 +
                                               ((kc * 32 + lr * 8) ^ rsw));
            s[n2] = __builtin_amdgcn_mfma_f32_16x16x32_bf16(qf[kc], kf, s[n2], 0, 0, 0);
          }
        }
      }
      __builtin_amdgcn_s_setprio(0);

      // ---- causal mask (boundary tiles only; live groups) ----
      if (kb0 + 63 > row0) {
        const int qi = row0 + lr * 4;
        #pragma unroll
        for (int n2 = 0; n2 < 4; ++n2) {
          if (n2 < ng2) {
            const int kvi = kb0 + n2 * 16 + lm;
            #pragma unroll
            for (int j = 0; j < 4; ++j)
              if (kvi > qi + j) s[n2][j] = -1e30f;
          }
        }
      }

      // ---- fast softmax: P = exp(S - m_stale), live groups only ----
      float pm = 0.f;
      #pragma unroll
      for (int n2 = 0; n2 < 4; ++n2) {
        if (n2 < ng2) {
          #pragma unroll
          for (int j = 0; j < 4; ++j) {
            const float p = __expf(s[n2][j] - m_run[j]);
            s[n2][j] = p;
            pm = fmaxf(pm, p);
          }
        }
      }

      if (!__all(pm <= P_CAP)) {
        // slow path (rare): per-row P-max via shfl chains; rescale rows > e^8
        #pragma unroll
        for (int j = 0; j < 4; ++j) {
          float v = fmaxf(fmaxf(s[0][j], s[1][j]), fmaxf(s[2][j], s[3][j]));
          v = fmaxf(v, __shfl_xor(v, 1, 64));
          v = fmaxf(v, __shfl_xor(v, 2, 64));
          v = fmaxf(v, __shfl_xor(v, 4, 64));
          v = fmaxf(v, __shfl_xor(v, 8, 64));
          if (v > P_CAP) {
            const float al = 1.0f / v;            // = exp(m_old - m_new)
            m_run[j] += __logf(v);
            lacc[j] *= al;
            #pragma unroll
            for (int n2 = 0; n2 < 4; ++n2) s[n2][j] *= al;
            #pragma unroll
            for (int ng = 0; ng < 8; ++ng) o[ng][j] *= al;
          }
        }
      }

      // ---- store P (swizzled; zeros for dead groups) ----
      #pragma unroll
      for (int j = 0; j < 4; ++j) {
        const int prow = lr * 4 + j;
        unsigned short* Pw = &Pl[w][prow * 64];
        const int sw = (prow & 7) << 3;
        Pw[lm ^ sw]        = f2bf(s[0][j]);
        Pw[(16 + lm) ^ sw] = f2bf(s[1][j]);
        Pw[(32 + lm) ^ sw] = f2bf(s[2][j]);
        Pw[(48 + lm) ^ sw] = f2bf(s[3][j]);
      }
      __asm__ volatile("s_waitcnt lgkmcnt(0)" ::: "memory");

      // ---- O += P V ;  l += P @ ones ----
      short8 pf[2];
      #pragma unroll
      for (int k2 = 0; k2 < 2; ++k2)
        pf[k2] = *(const short8*)(&Pl[w][lm * 64 + ((k2 * 32 + lr * 8) ^ rsw)]);
      __builtin_amdgcn_s_setprio(1);
      lacc = __builtin_amdgcn_mfma_f32_16x16x32_bf16(pf[0], ones, lacc, 0, 0, 0);
      lacc = __builtin_amdgcn_mfma_f32_16x16x32_bf16(pf[1], ones, lacc, 0, 0, 0);
      #pragma unroll
      for (int ng = 0; ng < 8; ++ng) {
        const short8 vf0 = *(const short8*)(Vc + (ng * 16 + lm) * 64 + ((lr * 8) ^ rsw));
        const short8 vf1 = *(const short8*)(Vc + (ng * 16 + lm) * 64 + ((32 + lr * 8) ^ rsw));
        o[ng] = __builtin_amdgcn_mfma_f32_16x16x32_bf16(pf[0], vf0, o[ng], 0, 0, 0);
        o[ng] = __builtin_amdgcn_mfma_f32_16x16x32_bf16(pf[1], vf1, o[ng], 0, 0, 0);
      }
      __builtin_amdgcn_s_setprio(0);
    }
    __syncthreads();
  }

  // ---- epilogue ----
  #pragma unroll
  for (int j = 0; j < 4; ++j) {
    const float linv = 1.0f / lacc[j];
    unsigned short* ar =
        att + ((size_t)(b * S_LEN) + row0 + lr * 4 + j) * (NH * DH) + h * DH + lm;
    #pragma unroll
    for (int ng = 0; ng < 8; ++ng) ar[ng * 16] = f2bf(o[ng][j] * linv);
  }
}

// ---------------------------------------------------------------------------
extern "C" void kernel_launch(void* const* d_in, const int* in_sizes, int n_in,
                              void* d_out, int out_size, void* d_ws, size_t ws_size,
                              hipStream_t stream) {
  const int*   positions = (const int*)  d_in[0];
  const float* hidden    = (const float*)d_in[1];
  const float* w_qkv     = (const float*)d_in[2];
  const float* w_o       = (const float*)d_in[3];
  const float* q_norm_w  = (const float*)d_in[4];
  const float* k_norm_w  = (const float*)d_in[5];
  float* out = (float*)d_out;

  // Workspace map (disjoint w.r.t. concurrent writers; R21 fix):
  //   ws[ 0.0M, 25.2M)  qkvb / att(reuse)
  //   ws[25.2M, 33.6M)  wot
  //   ws[50.3M, 67.1M)  hb / Qb(reuse)
  //   ws[67.1M, 79.7M)  wqkvt (dies after qkv GEMM)
  //   ws[67.1M, 71.3M)  Kb ; ws[71.3M, 75.5M) Vt (written after wqkvt dead)
  char* ws = (char*)d_ws;
  unsigned short* qkvb  = (unsigned short*)ws;
  unsigned short* att   = (unsigned short*)ws;
  unsigned short* wot   = (unsigned short*)(ws + 25165824);
  char* region = ws + (size_t)TOKS * QKV_N * 4;                 // +50,331,648
  unsigned short* hb    = (unsigned short*)region;
  unsigned short* Qb    = (unsigned short*)region;
  unsigned short* wqkvt = (unsigned short*)(region + 16777216);
  unsigned short* Kb    = (unsigned short*)(region + 16777216);
  unsigned short* Vt    = (unsigned short*)(region + 20971520);

  prep_all<<<dim3(64, 224), 256, 0, stream>>>(hidden, w_qkv, w_o, hb, wqkvt, wot);
  gemm256<1, 256><<<dim3(QKV_N / 256, TOKS / 256), 512, 0, stream>>>(
      hb, wqkvt, qkvb, TOKS, QKV_N, HS);
  norm_rope_v<<<dim3(TOKS, 6), 256, 0, stream>>>(
      qkvb, positions, q_norm_w, k_norm_w, Qb, Kb, Vt);
  attn_mfma<<<dim3(16, NH, 2), 512, 0, stream>>>(Qb, Kb, Vt, att);
  gemm256<0, 128><<<dim3(HS / 128, TOKS / 256), 512, 0, stream>>>(
      att, wot, out, TOKS, HS, HS);
}